// Round 2
// baseline (240.000 us; speedup 1.0000x reference)
//
#include <hip/hip_runtime.h>
#include <hip/hip_bf16.h>

// LSTM autoencoder: B=4096, T=128, F=32, H=64, 4H=256.
// One block per 16 batch rows (grid=256, 1 block/CU). 4 waves; wave w owns
// gate columns {i,f,g,o} x [16w,16w+16) so the cell update is pure per-lane.
// NUMERICS: the reference explodes to ~5.8e9 (relu LSTM positive feedback),
// so plain bf16 weights shift the growth rate fatally. All matmuls use the
// bf16x3 split scheme: v = hi + lo (two bf16), product = 3 MFMAs
// (hi*hi + hi*lo + lo*hi), giving ~2^-16 per-op relative error.
// h is exchanged per step via a swizzled LDS double buffer (hi & lo planes);
// c stays fp32 in registers.

typedef __bf16 bf16x8 __attribute__((ext_vector_type(8)));
typedef float f32x4 __attribute__((ext_vector_type(4)));
typedef float f32x8 __attribute__((ext_vector_type(8)));

struct frag2 { bf16x8 hi, lo; };

__device__ __forceinline__ float sigmoidf_(float v) {
    return 1.0f / (1.0f + __expf(-v));
}

__device__ __forceinline__ f32x4 mfma3(const frag2& a, const frag2& b, f32x4 c) {
    c = __builtin_amdgcn_mfma_f32_16x16x32_bf16(a.hi, b.hi, c, 0, 0, 0);
    c = __builtin_amdgcn_mfma_f32_16x16x32_bf16(a.lo, b.hi, c, 0, 0, 0);
    c = __builtin_amdgcn_mfma_f32_16x16x32_bf16(a.hi, b.lo, c, 0, 0, 0);
    return c;
}

// hi/lo B-fragment of a [K x LD] row-major fp32 matrix for mfma 16x16x32:
// lane l, elem e -> M[k0 + (l>>4)*8 + e][col]
template<int LD>
__device__ __forceinline__ frag2 load_fragB2(const float* __restrict__ M,
                                             int k0, int col, int lq) {
    frag2 r;
    const float* p = M + (size_t)(k0 + lq * 8) * LD + col;
#pragma unroll
    for (int e = 0; e < 8; ++e) {
        float v = p[(size_t)e * LD];
        __bf16 h = (__bf16)v;
        r.hi[e] = h;
        r.lo[e] = (__bf16)(v - (float)h);
    }
    return r;
}

__device__ __forceinline__ frag2 split_vec(f32x8 v) {
    frag2 r;
#pragma unroll
    for (int e = 0; e < 8; ++e) {
        __bf16 h = (__bf16)v[e];
        r.hi[e] = h;
        r.lo[e] = (__bf16)(v[e] - (float)h);
    }
    return r;
}

// swizzled byte offset inside one 16x64 bf16 h-tile (row = batch, 128B/row)
__device__ __forceinline__ int swz(int row, int byteoff) {
    return row * 128 + (byteoff ^ ((row & 7) << 4));
}

__global__ __launch_bounds__(256)
void lstm_ae_kernel(const float* __restrict__ x,
                    const float* __restrict__ eW, const float* __restrict__ eU,
                    const float* __restrict__ eb,
                    const float* __restrict__ dW, const float* __restrict__ dU,
                    const float* __restrict__ db,
                    const float* __restrict__ nW, const float* __restrict__ nb,
                    float* __restrict__ out)
{
    const int tid = threadIdx.x;
    const int wv  = tid >> 6;        // wave 0..3
    const int ln  = tid & 63;
    const int l16 = ln & 15;
    const int lq  = ln >> 4;         // 0..3
    const int b0  = blockIdx.x << 4; // 16 batch rows per block
    const int wcol = wv * 16 + l16;  // this wave's column within each gate

    // [buffer][hi/lo] planes of a 16x64 bf16 tile, XOR-swizzled
    __shared__ __align__(16) unsigned char hraw[2][2][2048];

    // ---------------- encoder weights (hi/lo register fragments) -------------
    frag2 W2[4], U2[4][2];
    float bz[4];
#pragma unroll
    for (int g = 0; g < 4; ++g) {
        W2[g]    = load_fragB2<256>(eW, 0,  g * 64 + wcol, lq);
        U2[g][0] = load_fragB2<256>(eU, 0,  g * 64 + wcol, lq);
        U2[g][1] = load_fragB2<256>(eU, 32, g * 64 + wcol, lq);
        bz[g]    = eb[g * 64 + wcol];
    }

    f32x4 cs = {0.f, 0.f, 0.f, 0.f};
    frag2 ha0, ha1;
#pragma unroll
    for (int e = 0; e < 8; ++e) {
        ha0.hi[e] = (__bf16)0.f; ha0.lo[e] = (__bf16)0.f;
        ha1.hi[e] = (__bf16)0.f; ha1.lo[e] = (__bf16)0.f;
    }

    // 2-deep x prefetch pipeline (stream from HBM, ~900cy latency)
    const float* xbase = x + (size_t)(b0 + l16) * 128 * 32 + lq * 8;
    f32x8 xv0 = *(const f32x8*)(xbase);
    f32x8 xv1 = *(const f32x8*)(xbase + 32);

    int q = 0;
    // ---------------- encoder scan ----------------
    for (int t = 0; t < 128; ++t) {
        const int tn = (t + 2 < 128) ? (t + 2) : 127;
        f32x8 xv2 = *(const f32x8*)(xbase + (size_t)tn * 32);

        frag2 xa2 = split_vec(xv0);

        f32x4 z[4];
#pragma unroll
        for (int g = 0; g < 4; ++g) {
            f32x4 zc = {bz[g], bz[g], bz[g], bz[g]};
            zc = mfma3(xa2, W2[g],    zc);
            zc = mfma3(ha0, U2[g][0], zc);
            zc = mfma3(ha1, U2[g][1], zc);
            z[g] = zc;
        }
#pragma unroll
        for (int r = 0; r < 4; ++r) {
            float ig = sigmoidf_(z[0][r]);
            float fg = sigmoidf_(z[1][r]);
            float gg = fmaxf(z[2][r], 0.f);
            float og = sigmoidf_(z[3][r]);
            cs[r] = fg * cs[r] + ig * gg;
            float hv = og * fmaxf(cs[r], 0.f);
            __bf16 hh = (__bf16)hv;
            __bf16 hl = (__bf16)(hv - (float)hh);
            const int off = swz(lq * 4 + r, wcol * 2);
            *(__bf16*)(hraw[q][0] + off) = hh;
            *(__bf16*)(hraw[q][1] + off) = hl;
        }
        __syncthreads();
        ha0.hi = *(const bf16x8*)(hraw[q][0] + swz(l16, lq * 16));
        ha0.lo = *(const bf16x8*)(hraw[q][1] + swz(l16, lq * 16));
        ha1.hi = *(const bf16x8*)(hraw[q][0] + swz(l16, 64 + lq * 16));
        ha1.lo = *(const bf16x8*)(hraw[q][1] + swz(l16, 64 + lq * 16));
        q ^= 1;
        xv0 = xv1; xv1 = xv2;
    }
    // ha0/ha1 now hold the encoded state (hi/lo A-fragments).

    // ------- decoder constant input projection zx = encoded@dW + db -------
    frag2 dU2[4][2];
    f32x4 zx[4];
#pragma unroll
    for (int g = 0; g < 4; ++g) {
        frag2 w0 = load_fragB2<256>(dW, 0,  g * 64 + wcol, lq);
        frag2 w1 = load_fragB2<256>(dW, 32, g * 64 + wcol, lq);
        dU2[g][0] = load_fragB2<256>(dU, 0,  g * 64 + wcol, lq);
        dU2[g][1] = load_fragB2<256>(dU, 32, g * 64 + wcol, lq);
        float bb = db[g * 64 + wcol];
        f32x4 zc = {bb, bb, bb, bb};
        zc = mfma3(ha0, w0, zc);
        zc = mfma3(ha1, w1, zc);
        zx[g] = zc;
    }
    // dense weights (waves 0,1: N-tiles of 16 over F=32)
    frag2 DN2[2];
    float ob = 0.f;
    if (wv < 2) {
        DN2[0] = load_fragB2<32>(nW, 0,  wv * 16 + l16, lq);
        DN2[1] = load_fragB2<32>(nW, 32, wv * 16 + l16, lq);
        ob     = nb[wv * 16 + l16];
    }

#pragma unroll
    for (int e = 0; e < 8; ++e) {
        ha0.hi[e] = (__bf16)0.f; ha0.lo[e] = (__bf16)0.f;
        ha1.hi[e] = (__bf16)0.f; ha1.lo[e] = (__bf16)0.f;
    }
    cs[0] = cs[1] = cs[2] = cs[3] = 0.f;
    q = 0;
    // ---------------- decoder scan + fused dense ----------------
    for (int t = 0; t < 128; ++t) {
        f32x4 z[4];
#pragma unroll
        for (int g = 0; g < 4; ++g) {
            f32x4 zc = zx[g];
            zc = mfma3(ha0, dU2[g][0], zc);
            zc = mfma3(ha1, dU2[g][1], zc);
            z[g] = zc;
        }
#pragma unroll
        for (int r = 0; r < 4; ++r) {
            float ig = sigmoidf_(z[0][r]);
            float fg = sigmoidf_(z[1][r]);
            float gg = fmaxf(z[2][r], 0.f);
            float og = sigmoidf_(z[3][r]);
            cs[r] = fg * cs[r] + ig * gg;
            float hv = og * fmaxf(cs[r], 0.f);
            __bf16 hh = (__bf16)hv;
            __bf16 hl = (__bf16)(hv - (float)hh);
            const int off = swz(lq * 4 + r, wcol * 2);
            *(__bf16*)(hraw[q][0] + off) = hh;
            *(__bf16*)(hraw[q][1] + off) = hl;
        }
        __syncthreads();
        ha0.hi = *(const bf16x8*)(hraw[q][0] + swz(l16, lq * 16));
        ha0.lo = *(const bf16x8*)(hraw[q][1] + swz(l16, lq * 16));
        ha1.hi = *(const bf16x8*)(hraw[q][0] + swz(l16, 64 + lq * 16));
        ha1.lo = *(const bf16x8*)(hraw[q][1] + swz(l16, 64 + lq * 16));
        // fused dense: out[b][t][:] = h_t @ nW + nb
        if (wv < 2) {
            f32x4 oa = {ob, ob, ob, ob};
            oa = mfma3(ha0, DN2[0], oa);
            oa = mfma3(ha1, DN2[1], oa);
#pragma unroll
            for (int r = 0; r < 4; ++r)
                out[((size_t)(b0 + lq * 4 + r) * 128 + t) * 32 + wv * 16 + l16] = oa[r];
        }
        q ^= 1;
    }
}

extern "C" void kernel_launch(void* const* d_in, const int* in_sizes, int n_in,
                              void* d_out, int out_size, void* d_ws, size_t ws_size,
                              hipStream_t stream) {
    const float* x  = (const float*)d_in[0];
    const float* eW = (const float*)d_in[1];
    const float* eU = (const float*)d_in[2];
    const float* eb = (const float*)d_in[3];
    const float* dW = (const float*)d_in[4];
    const float* dU = (const float*)d_in[5];
    const float* db = (const float*)d_in[6];
    const float* nW = (const float*)d_in[7];
    const float* nb = (const float*)d_in[8];
    float* out = (float*)d_out;

    hipLaunchKernelGGL(lstm_ae_kernel, dim3(4096 / 16), dim3(256), 0, stream,
                       x, eW, eU, eb, dW, dU, db, nW, nb, out);
}

// Round 3
// 229.787 us; speedup vs baseline: 1.0444x; 1.0444x over previous
//
#include <hip/hip_runtime.h>
#include <hip/hip_bf16.h>

// LSTM autoencoder: B=4096, T=128, F=32, H=64, 4H=256.
// One block per 16 batch rows (grid=256, 1 block/CU). 4 waves; wave w owns
// gate columns {i,f,g,o} x [16w,16w+16) so the cell update is pure per-lane.
// NUMERICS: reference explodes to ~5.8e9 (relu LSTM positive feedback); all
// matmuls use bf16x3 split (hi+lo, 3 MFMAs) for ~2^-16 per-op error.
// h exchanged per step via swizzled LDS double buffer (hi & lo planes).
// __launch_bounds__(256,1): grid==1 block/CU, so claim the full VGPR budget
// to keep all weight fragments resident (round-2 cap of 108 VGPRs caused
// per-step rematerialization of weight frags = dominant VALU cost).

typedef __bf16 bf16x8 __attribute__((ext_vector_type(8)));
typedef float f32x4 __attribute__((ext_vector_type(4)));
typedef float f32x8 __attribute__((ext_vector_type(8)));

struct frag2 { bf16x8 hi, lo; };

__device__ __forceinline__ float sigmoidf_(float v) {
    return 1.0f / (1.0f + __expf(-v));
}

__device__ __forceinline__ f32x4 mfma3(const frag2& a, const frag2& b, f32x4 c) {
    c = __builtin_amdgcn_mfma_f32_16x16x32_bf16(a.hi, b.hi, c, 0, 0, 0);
    c = __builtin_amdgcn_mfma_f32_16x16x32_bf16(a.lo, b.hi, c, 0, 0, 0);
    c = __builtin_amdgcn_mfma_f32_16x16x32_bf16(a.hi, b.lo, c, 0, 0, 0);
    return c;
}

// hi/lo B-fragment of a [K x LD] row-major fp32 matrix for mfma 16x16x32:
// lane l, elem e -> M[k0 + (l>>4)*8 + e][col]
template<int LD>
__device__ __forceinline__ frag2 load_fragB2(const float* __restrict__ M,
                                             int k0, int col, int lq) {
    frag2 r;
    const float* p = M + (size_t)(k0 + lq * 8) * LD + col;
#pragma unroll
    for (int e = 0; e < 8; ++e) {
        float v = p[(size_t)e * LD];
        __bf16 h = (__bf16)v;
        r.hi[e] = h;
        r.lo[e] = (__bf16)(v - (float)h);
    }
    return r;
}

__device__ __forceinline__ frag2 split_vec(f32x8 v) {
    frag2 r;
#pragma unroll
    for (int e = 0; e < 8; ++e) {
        __bf16 h = (__bf16)v[e];
        r.hi[e] = h;
        r.lo[e] = (__bf16)(v[e] - (float)h);
    }
    return r;
}

// swizzled byte offset inside one 16x64 bf16 h-tile (row = batch, 128B/row)
__device__ __forceinline__ int swz(int row, int byteoff) {
    return row * 128 + (byteoff ^ ((row & 7) << 4));
}

__global__ __launch_bounds__(256, 1)
void lstm_ae_kernel(const float* __restrict__ x,
                    const float* __restrict__ eW, const float* __restrict__ eU,
                    const float* __restrict__ eb,
                    const float* __restrict__ dW, const float* __restrict__ dU,
                    const float* __restrict__ db,
                    const float* __restrict__ nW, const float* __restrict__ nb,
                    float* __restrict__ out)
{
    const int tid = threadIdx.x;
    const int wv  = tid >> 6;        // wave 0..3
    const int ln  = tid & 63;
    const int l16 = ln & 15;
    const int lq  = ln >> 4;         // 0..3
    const int b0  = blockIdx.x << 4; // 16 batch rows per block
    const int wcol = wv * 16 + l16;  // this wave's column within each gate

    // [buffer][hi/lo] planes of a 16x64 bf16 tile, XOR-swizzled
    __shared__ __align__(16) unsigned char hraw[2][2][2048];

    // loop-invariant LDS byte offsets
    int offw[4];
#pragma unroll
    for (int r = 0; r < 4; ++r) offw[r] = swz(lq * 4 + r, wcol * 2);
    const int offr0 = swz(l16, lq * 16);
    const int offr1 = swz(l16, 64 + lq * 16);

    // ---------------- encoder weights (hi/lo register fragments) -------------
    frag2 W2[4], U2[4][2];
    float bz[4];
#pragma unroll
    for (int g = 0; g < 4; ++g) {
        W2[g]    = load_fragB2<256>(eW, 0,  g * 64 + wcol, lq);
        U2[g][0] = load_fragB2<256>(eU, 0,  g * 64 + wcol, lq);
        U2[g][1] = load_fragB2<256>(eU, 32, g * 64 + wcol, lq);
        bz[g]    = eb[g * 64 + wcol];
    }

    f32x4 cs = {0.f, 0.f, 0.f, 0.f};
    frag2 ha0, ha1;
#pragma unroll
    for (int e = 0; e < 8; ++e) {
        ha0.hi[e] = (__bf16)0.f; ha0.lo[e] = (__bf16)0.f;
        ha1.hi[e] = (__bf16)0.f; ha1.lo[e] = (__bf16)0.f;
    }

    // 2-deep x prefetch pipeline (stream from HBM)
    const float* xbase = x + (size_t)(b0 + l16) * 128 * 32 + lq * 8;
    f32x8 xv0 = *(const f32x8*)(xbase);
    f32x8 xv1 = *(const f32x8*)(xbase + 32);

    int q = 0;
    // ---------------- encoder scan ----------------
#pragma unroll 2
    for (int t = 0; t < 128; ++t) {
        const int tn = (t + 2 < 128) ? (t + 2) : 127;
        f32x8 xv2 = *(const f32x8*)(xbase + (size_t)tn * 32);

        frag2 xa2 = split_vec(xv0);

        f32x4 z[4];
#pragma unroll
        for (int g = 0; g < 4; ++g) {
            f32x4 zc = {bz[g], bz[g], bz[g], bz[g]};
            zc = mfma3(xa2, W2[g],    zc);
            zc = mfma3(ha0, U2[g][0], zc);
            zc = mfma3(ha1, U2[g][1], zc);
            z[g] = zc;
        }
#pragma unroll
        for (int r = 0; r < 4; ++r) {
            float ig = sigmoidf_(z[0][r]);
            float fg = sigmoidf_(z[1][r]);
            float gg = fmaxf(z[2][r], 0.f);
            float og = sigmoidf_(z[3][r]);
            cs[r] = fg * cs[r] + ig * gg;
            float hv = og * fmaxf(cs[r], 0.f);
            __bf16 hh = (__bf16)hv;
            __bf16 hl = (__bf16)(hv - (float)hh);
            *(__bf16*)(hraw[q][0] + offw[r]) = hh;
            *(__bf16*)(hraw[q][1] + offw[r]) = hl;
        }
        __syncthreads();
        ha0.hi = *(const bf16x8*)(hraw[q][0] + offr0);
        ha0.lo = *(const bf16x8*)(hraw[q][1] + offr0);
        ha1.hi = *(const bf16x8*)(hraw[q][0] + offr1);
        ha1.lo = *(const bf16x8*)(hraw[q][1] + offr1);
        q ^= 1;
        xv0 = xv1; xv1 = xv2;
    }
    // ha0/ha1 now hold the encoded state (hi/lo A-fragments).

    // ------- decoder constant input projection zx = encoded@dW + db -------
    frag2 dU2[4][2];
    f32x4 zx[4];
#pragma unroll
    for (int g = 0; g < 4; ++g) {
        frag2 w0 = load_fragB2<256>(dW, 0,  g * 64 + wcol, lq);
        frag2 w1 = load_fragB2<256>(dW, 32, g * 64 + wcol, lq);
        dU2[g][0] = load_fragB2<256>(dU, 0,  g * 64 + wcol, lq);
        dU2[g][1] = load_fragB2<256>(dU, 32, g * 64 + wcol, lq);
        float bb = db[g * 64 + wcol];
        f32x4 zc = {bb, bb, bb, bb};
        zc = mfma3(ha0, w0, zc);
        zc = mfma3(ha1, w1, zc);
        zx[g] = zc;
    }
    // dense weights (waves 0,1: N-tiles of 16 over F=32)
    frag2 DN2[2];
    float ob = 0.f;
    if (wv < 2) {
        DN2[0] = load_fragB2<32>(nW, 0,  wv * 16 + l16, lq);
        DN2[1] = load_fragB2<32>(nW, 32, wv * 16 + l16, lq);
        ob     = nb[wv * 16 + l16];
    }

#pragma unroll
    for (int e = 0; e < 8; ++e) {
        ha0.hi[e] = (__bf16)0.f; ha0.lo[e] = (__bf16)0.f;
        ha1.hi[e] = (__bf16)0.f; ha1.lo[e] = (__bf16)0.f;
    }
    cs[0] = cs[1] = cs[2] = cs[3] = 0.f;
    q = 0;
    // ---------------- decoder scan + fused dense ----------------
#pragma unroll 2
    for (int t = 0; t < 128; ++t) {
        f32x4 z[4];
#pragma unroll
        for (int g = 0; g < 4; ++g) {
            f32x4 zc = zx[g];
            zc = mfma3(ha0, dU2[g][0], zc);
            zc = mfma3(ha1, dU2[g][1], zc);
            z[g] = zc;
        }
#pragma unroll
        for (int r = 0; r < 4; ++r) {
            float ig = sigmoidf_(z[0][r]);
            float fg = sigmoidf_(z[1][r]);
            float gg = fmaxf(z[2][r], 0.f);
            float og = sigmoidf_(z[3][r]);
            cs[r] = fg * cs[r] + ig * gg;
            float hv = og * fmaxf(cs[r], 0.f);
            __bf16 hh = (__bf16)hv;
            __bf16 hl = (__bf16)(hv - (float)hh);
            *(__bf16*)(hraw[q][0] + offw[r]) = hh;
            *(__bf16*)(hraw[q][1] + offw[r]) = hl;
        }
        __syncthreads();
        ha0.hi = *(const bf16x8*)(hraw[q][0] + offr0);
        ha0.lo = *(const bf16x8*)(hraw[q][1] + offr0);
        ha1.hi = *(const bf16x8*)(hraw[q][0] + offr1);
        ha1.lo = *(const bf16x8*)(hraw[q][1] + offr1);
        // fused dense: out[b][t][:] = h_t @ nW + nb
        if (wv < 2) {
            f32x4 oa = {ob, ob, ob, ob};
            oa = mfma3(ha0, DN2[0], oa);
            oa = mfma3(ha1, DN2[1], oa);
#pragma unroll
            for (int r = 0; r < 4; ++r)
                out[((size_t)(b0 + lq * 4 + r) * 128 + t) * 32 + wv * 16 + l16] = oa[r];
        }
        q ^= 1;
    }
}

extern "C" void kernel_launch(void* const* d_in, const int* in_sizes, int n_in,
                              void* d_out, int out_size, void* d_ws, size_t ws_size,
                              hipStream_t stream) {
    const float* x  = (const float*)d_in[0];
    const float* eW = (const float*)d_in[1];
    const float* eU = (const float*)d_in[2];
    const float* eb = (const float*)d_in[3];
    const float* dW = (const float*)d_in[4];
    const float* dU = (const float*)d_in[5];
    const float* db = (const float*)d_in[6];
    const float* nW = (const float*)d_in[7];
    const float* nb = (const float*)d_in[8];
    float* out = (float*)d_out;

    hipLaunchKernelGGL(lstm_ae_kernel, dim3(4096 / 16), dim3(256), 0, stream,
                       x, eW, eU, eb, dW, dU, db, nW, nb, out);
}